// Round 3
// baseline (2162.430 us; speedup 1.0000x reference)
//
#include <hip/hip_runtime.h>
#include <math.h>

// Problem constants
#define DEPTH 2
#define DIM   512
#define HEADS 8
#define DH    64
#define INNER 512
#define MLP_D 2048
#define BSZ   2
#define SEQ   2048
#define MROWS (BSZ*SEQ)          // 4096
#define SCALE 0.125f             // DH^-0.5
#define LN_EPS 1e-5f

typedef unsigned short u16;
typedef unsigned int   u32;
typedef __attribute__((ext_vector_type(8))) unsigned short u16x8;
typedef __attribute__((ext_vector_type(4))) unsigned short u16x4;
typedef __attribute__((ext_vector_type(8))) short          s16x8;
typedef __attribute__((ext_vector_type(4))) float          f32x4;

// fp32 -> bf16 round-to-nearest-even
__device__ __forceinline__ u16 f2bf(float f) {
    u32 u = __float_as_uint(f);
    u += 0x7fffu + ((u >> 16) & 1u);
    return (u16)(u >> 16);
}

__device__ __forceinline__ float wred_sum(float v) {
    #pragma unroll
    for (int o = 32; o; o >>= 1) v += __shfl_xor(v, o);
    return v;
}

// ---------------------------------------------------------------------------
// LayerNorm: one wave per row of 512; outputs bf16. 4 waves/block.
// ---------------------------------------------------------------------------
__global__ __launch_bounds__(256) void ln_kernel(
    const float* __restrict__ x,   // [MROWS, DIM] f32
    const float* __restrict__ g,
    const float* __restrict__ b,
    u16* __restrict__ y)           // [MROWS, DIM] bf16
{
    const int wave = threadIdx.x >> 6;
    const int lane = threadIdx.x & 63;
    const int row  = blockIdx.x * 4 + wave;
    const float* xr = x + (size_t)row * DIM;

    float4 v0 = *reinterpret_cast<const float4*>(&xr[lane * 8]);
    float4 v1 = *reinterpret_cast<const float4*>(&xr[lane * 8 + 4]);

    float s = v0.x + v0.y + v0.z + v0.w + v1.x + v1.y + v1.z + v1.w;
    s = wred_sum(s);
    const float mean = s * (1.0f / DIM);

    float d[8] = {v0.x - mean, v0.y - mean, v0.z - mean, v0.w - mean,
                  v1.x - mean, v1.y - mean, v1.z - mean, v1.w - mean};
    float ss = 0.f;
    #pragma unroll
    for (int i = 0; i < 8; ++i) ss += d[i] * d[i];
    ss = wred_sum(ss);
    const float inv = rsqrtf(ss * (1.0f / DIM) + LN_EPS);

    float4 g0 = *reinterpret_cast<const float4*>(&g[lane * 8]);
    float4 g1 = *reinterpret_cast<const float4*>(&g[lane * 8 + 4]);
    float4 b0 = *reinterpret_cast<const float4*>(&b[lane * 8]);
    float4 b1 = *reinterpret_cast<const float4*>(&b[lane * 8 + 4]);
    const float gg[8] = {g0.x, g0.y, g0.z, g0.w, g1.x, g1.y, g1.z, g1.w};
    const float bb[8] = {b0.x, b0.y, b0.z, b0.w, b1.x, b1.y, b1.z, b1.w};

    u16x8 o;
    #pragma unroll
    for (int i = 0; i < 8; ++i) o[i] = f2bf(d[i] * inv * gg[i] + bb[i]);
    *reinterpret_cast<u16x8*>(&y[(size_t)row * DIM + lane * 8]) = o;
}

// ---------------------------------------------------------------------------
// Transpose-convert: in f32 [K,N] -> out bf16 [N,K]. 64x64 tiles, 256 thr.
// ---------------------------------------------------------------------------
__global__ __launch_bounds__(256) void transpose_bf16_kernel(
    const float* __restrict__ in, u16* __restrict__ out, int K, int N)
{
    __shared__ u16 t[64][65];
    const int k0 = blockIdx.y * 64, n0 = blockIdx.x * 64;
    const int tid = threadIdx.x;
    #pragma unroll
    for (int i = 0; i < 4; ++i) {
        int idx = tid + i * 256;
        int r = idx >> 4, c4 = idx & 15;
        float4 v = *reinterpret_cast<const float4*>(&in[(size_t)(k0 + r) * N + n0 + c4 * 4]);
        t[c4 * 4 + 0][r] = f2bf(v.x);
        t[c4 * 4 + 1][r] = f2bf(v.y);
        t[c4 * 4 + 2][r] = f2bf(v.z);
        t[c4 * 4 + 3][r] = f2bf(v.w);
    }
    __syncthreads();
    #pragma unroll
    for (int i = 0; i < 2; ++i) {
        int idx = tid + i * 256;
        int r = idx >> 3, c8 = idx & 7;
        u16x8 w;
        #pragma unroll
        for (int j = 0; j < 8; ++j) w[j] = t[r][c8 * 8 + j];
        *reinterpret_cast<u16x8*>(&out[(size_t)(n0 + r) * K + k0 + c8 * 8]) = w;
    }
}

// ---------------------------------------------------------------------------
// bf16 MFMA GEMM: C = epi(A @ B [+bias] [+Cin])
//   A: [M,K] bf16 row-major. BT: [N,K] bf16 row-major (B transposed).
//   EPI 0: Cout f32 = acc
//   EPI 1: Cout bf16 = gelu(acc + bias)
//   EPI 2: Cout f32 = Cin + acc + bias   (Cin==Cout ok)
// 256 threads = 4 waves (2x2). Wave tile (MT*16)x(NT*16). BK=32.
// LDS rows padded to 40 u16 (80B) -> 2-way max bank conflict on b128 reads.
// ---------------------------------------------------------------------------
template<int BM, int BN, int MT, int NT, int EPI>
__global__ __launch_bounds__(256) void gemm_bf16(
    const u16* __restrict__ A, const u16* __restrict__ BT,
    const float* __restrict__ bias, const float* __restrict__ Cin,
    void* __restrict__ CoutV, int M, int N, int K)
{
    constexpr int BK = 32;
    constexpr int LDW = 40;                 // padded row stride (u16)
    constexpr int WC = BN / (NT * 16);      // waves along N
    constexpr int AR = (BM * BK) / (256 * 8);
    constexpr int BR = (BN * BK) / (256 * 8);

    __shared__ __align__(16) u16 As[BM * LDW];
    __shared__ __align__(16) u16 Bs[BN * LDW];

    const int tid  = threadIdx.x;
    const int lane = tid & 63;
    const int wid  = tid >> 6;
    const int wr   = wid / WC, wc = wid % WC;
    const int lr   = lane & 15, lk = lane >> 4;
    const int bm   = blockIdx.y * BM, bn = blockIdx.x * BN;

    f32x4 acc[MT][NT];
    #pragma unroll
    for (int i = 0; i < MT; ++i)
        #pragma unroll
        for (int j = 0; j < NT; ++j) {
            acc[i][j][0] = 0.f; acc[i][j][1] = 0.f;
            acc[i][j][2] = 0.f; acc[i][j][3] = 0.f;
        }

    u16x8 ar[AR], br[BR];
    // prefetch tile 0
    #pragma unroll
    for (int i = 0; i < AR; ++i) {
        int idx = tid + i * 256, row = idx >> 2, k16 = idx & 3;
        ar[i] = *reinterpret_cast<const u16x8*>(&A[(size_t)(bm + row) * K + k16 * 8]);
    }
    #pragma unroll
    for (int i = 0; i < BR; ++i) {
        int idx = tid + i * 256, row = idx >> 2, k16 = idx & 3;
        br[i] = *reinterpret_cast<const u16x8*>(&BT[(size_t)(bn + row) * K + k16 * 8]);
    }

    const int NTILES = K / BK;
    for (int t = 0; t < NTILES; ++t) {
        __syncthreads();               // previous tile's reads complete
        #pragma unroll
        for (int i = 0; i < AR; ++i) {
            int idx = tid + i * 256, row = idx >> 2, k16 = idx & 3;
            *reinterpret_cast<u16x8*>(&As[row * LDW + k16 * 8]) = ar[i];
        }
        #pragma unroll
        for (int i = 0; i < BR; ++i) {
            int idx = tid + i * 256, row = idx >> 2, k16 = idx & 3;
            *reinterpret_cast<u16x8*>(&Bs[row * LDW + k16 * 8]) = br[i];
        }
        __syncthreads();               // tile ready

        if (t + 1 < NTILES) {          // prefetch next (overlaps MFMA below)
            const int k0 = (t + 1) * BK;
            #pragma unroll
            for (int i = 0; i < AR; ++i) {
                int idx = tid + i * 256, row = idx >> 2, k16 = idx & 3;
                ar[i] = *reinterpret_cast<const u16x8*>(&A[(size_t)(bm + row) * K + k0 + k16 * 8]);
            }
            #pragma unroll
            for (int i = 0; i < BR; ++i) {
                int idx = tid + i * 256, row = idx >> 2, k16 = idx & 3;
                br[i] = *reinterpret_cast<const u16x8*>(&BT[(size_t)(bn + row) * K + k0 + k16 * 8]);
            }
        }

        s16x8 af[MT], bf[NT];
        #pragma unroll
        for (int mt = 0; mt < MT; ++mt)
            af[mt] = *reinterpret_cast<const s16x8*>(&As[(wr * MT * 16 + mt * 16 + lr) * LDW + lk * 8]);
        #pragma unroll
        for (int nt = 0; nt < NT; ++nt)
            bf[nt] = *reinterpret_cast<const s16x8*>(&Bs[(wc * NT * 16 + nt * 16 + lr) * LDW + lk * 8]);
        #pragma unroll
        for (int mt = 0; mt < MT; ++mt)
            #pragma unroll
            for (int nt = 0; nt < NT; ++nt)
                acc[mt][nt] = __builtin_amdgcn_mfma_f32_16x16x32_bf16(
                    af[mt], bf[nt], acc[mt][nt], 0, 0, 0);
    }

    // epilogue: lane holds D[row = lk*4+i][col = lr] per 16x16 tile (m89-verified)
    #pragma unroll
    for (int mt = 0; mt < MT; ++mt) {
        #pragma unroll
        for (int i = 0; i < 4; ++i) {
            const size_t r = bm + wr * MT * 16 + mt * 16 + lk * 4 + i;
            #pragma unroll
            for (int nt = 0; nt < NT; ++nt) {
                const size_t c = bn + wc * NT * 16 + nt * 16 + lr;
                float v = acc[mt][nt][i];
                if (EPI == 0) {
                    ((float*)CoutV)[r * N + c] = v;
                } else if (EPI == 1) {
                    v += bias[c];
                    v = 0.5f * v * (1.0f + erff(v * 0.70710678118654752f));
                    ((u16*)CoutV)[r * N + c] = f2bf(v);
                } else {
                    v += bias[c] + Cin[r * N + c];
                    ((float*)CoutV)[r * N + c] = v;
                }
            }
        }
    }
}

// ---------------------------------------------------------------------------
// Flash-style attention (fp32), multiplicative mask + renorm; bf16 z output.
//   z_d = sum_j e_j*m_j*v_jd / (sum_j e_j*m_j + 1e-10 * sum_j e_j)
// Block 256 thr, 64 q-rows of one (b,h); 4x4 register tiles.
// ---------------------------------------------------------------------------
__global__ __launch_bounds__(256) void attn_kernel(
    const float* __restrict__ qkv,  // [MROWS, 3*INNER] f32
    const int*   __restrict__ mask, // [B, L, L]
    u16* __restrict__ z)            // [MROWS, INNER] bf16
{
    const int bh = blockIdx.x;
    const int b  = bh >> 3;
    const int h  = bh & 7;
    const int q0 = blockIdx.y * 64;
    const int tid = threadIdx.x;
    const int tx = tid & 15;
    const int ty = tid >> 4;

    __shared__ float Qs[64][65];   // [d][q], pre-scaled
    __shared__ float KPs[64][65];  // K phase: [d][k]; P phase: [k][q]
    __shared__ float Vs[64][65];   // [k][d]

    #pragma unroll
    for (int i = 0; i < 4; ++i) {
        int f   = tid + i * 256;
        int row = f >> 4;
        int c4  = f & 15;
        float4 v = *reinterpret_cast<const float4*>(
            &qkv[(size_t)(b * SEQ + q0 + row) * (3 * INNER) + h * DH + c4 * 4]);
        Qs[c4 * 4 + 0][row] = v.x * SCALE;
        Qs[c4 * 4 + 1][row] = v.y * SCALE;
        Qs[c4 * 4 + 2][row] = v.z * SCALE;
        Qs[c4 * 4 + 3][row] = v.w * SCALE;
    }

    float Mx[4], Sa[4], Sm[4];
    float zacc[4][4];
    #pragma unroll
    for (int i = 0; i < 4; ++i) {
        Mx[i] = -1e30f; Sa[i] = 0.f; Sm[i] = 0.f;
        #pragma unroll
        for (int j = 0; j < 4; ++j) zacc[i][j] = 0.f;
    }

    const size_t mbase = ((size_t)b * SEQ + q0 + ty * 4) * SEQ;

    for (int k0 = 0; k0 < SEQ; k0 += 64) {
        __syncthreads();

        #pragma unroll
        for (int i = 0; i < 4; ++i) {
            int f  = tid + i * 256;
            int kr = f >> 4;
            int c4 = f & 15;
            const float* kp = &qkv[(size_t)(b * SEQ + k0 + kr) * (3 * INNER)
                                   + INNER + h * DH + c4 * 4];
            float4 kv = *reinterpret_cast<const float4*>(kp);
            float4 vv = *reinterpret_cast<const float4*>(kp + INNER);
            KPs[c4 * 4 + 0][kr] = kv.x;
            KPs[c4 * 4 + 1][kr] = kv.y;
            KPs[c4 * 4 + 2][kr] = kv.z;
            KPs[c4 * 4 + 3][kr] = kv.w;
            *reinterpret_cast<float4*>(&Vs[kr][c4 * 4]) = vv;
        }
        __syncthreads();

        float s[4][4];
        #pragma unroll
        for (int i = 0; i < 4; ++i)
            #pragma unroll
            for (int j = 0; j < 4; ++j) s[i][j] = 0.f;
        #pragma unroll
        for (int d = 0; d < 64; ++d) {
            float4 a4 = *reinterpret_cast<const float4*>(&Qs[d][ty * 4]);
            float4 b4 = *reinterpret_cast<const float4*>(&KPs[d][tx * 4]);
            const float a[4]  = {a4.x, a4.y, a4.z, a4.w};
            const float bb[4] = {b4.x, b4.y, b4.z, b4.w};
            #pragma unroll
            for (int i = 0; i < 4; ++i)
                #pragma unroll
                for (int j = 0; j < 4; ++j)
                    s[i][j] = fmaf(a[i], bb[j], s[i][j]);
        }
        __syncthreads();   // K dead -> reuse buffer for P

        float em[4][4];
        #pragma unroll
        for (int i = 0; i < 4; ++i) {
            float mloc = fmaxf(fmaxf(s[i][0], s[i][1]), fmaxf(s[i][2], s[i][3]));
            #pragma unroll
            for (int o = 8; o; o >>= 1) mloc = fmaxf(mloc, __shfl_xor(mloc, o));
            const float Mn = fmaxf(Mx[i], mloc);
            const float r  = __expf(Mx[i] - Mn);
            Mx[i] = Mn;

            const int4 mr = *reinterpret_cast<const int4*>(
                &mask[mbase + (size_t)i * SEQ + k0 + tx * 4]);
            float e0 = __expf(s[i][0] - Mn);
            float e1 = __expf(s[i][1] - Mn);
            float e2 = __expf(s[i][2] - Mn);
            float e3 = __expf(s[i][3] - Mn);
            float ta = e0 + e1 + e2 + e3;
            em[i][0] = mr.x ? e0 : 0.f;
            em[i][1] = mr.y ? e1 : 0.f;
            em[i][2] = mr.z ? e2 : 0.f;
            em[i][3] = mr.w ? e3 : 0.f;
            float tm = em[i][0] + em[i][1] + em[i][2] + em[i][3];
            #pragma unroll
            for (int o = 8; o; o >>= 1) {
                ta += __shfl_xor(ta, o);
                tm += __shfl_xor(tm, o);
            }
            Sa[i] = Sa[i] * r + ta;
            Sm[i] = Sm[i] * r + tm;
            #pragma unroll
            for (int j = 0; j < 4; ++j) zacc[i][j] *= r;
        }
        #pragma unroll
        for (int j = 0; j < 4; ++j) {
            float4 p4;
            p4.x = em[0][j]; p4.y = em[1][j]; p4.z = em[2][j]; p4.w = em[3][j];
            *reinterpret_cast<float4*>(&KPs[tx * 4 + j][ty * 4]) = p4;
        }
        __syncthreads();

        #pragma unroll
        for (int k = 0; k < 64; ++k) {
            float4 a4 = *reinterpret_cast<const float4*>(&KPs[k][ty * 4]);
            float4 b4 = *reinterpret_cast<const float4*>(&Vs[k][tx * 4]);
            const float a[4]  = {a4.x, a4.y, a4.z, a4.w};
            const float bb[4] = {b4.x, b4.y, b4.z, b4.w};
            #pragma unroll
            for (int i = 0; i < 4; ++i)
                #pragma unroll
                for (int j = 0; j < 4; ++j)
                    zacc[i][j] = fmaf(a[i], bb[j], zacc[i][j]);
        }
    }

    #pragma unroll
    for (int i = 0; i < 4; ++i) {
        const float inv = 1.0f / (Sm[i] + 1e-10f * Sa[i]);
        u16x4 o;
        #pragma unroll
        for (int j = 0; j < 4; ++j) o[j] = f2bf(zacc[i][j] * inv);
        *reinterpret_cast<u16x4*>(
            &z[(size_t)(b * SEQ + q0 + ty * 4 + i) * INNER + h * DH + tx * 4]) = o;
    }
}

// ---------------------------------------------------------------------------
// Launch
// ---------------------------------------------------------------------------
extern "C" void kernel_launch(void* const* d_in, const int* in_sizes, int n_in,
                              void* d_out, int out_size, void* d_ws, size_t ws_size,
                              hipStream_t stream) {
    const float* x      = (const float*)d_in[0];
    const int*   mask   = (const int*)  d_in[1];
    const float* ln1_g  = (const float*)d_in[2];
    const float* ln1_b  = (const float*)d_in[3];
    const float* w_qkv  = (const float*)d_in[4];
    const float* w_out  = (const float*)d_in[5];
    const float* b_out  = (const float*)d_in[6];
    const float* ln2_g  = (const float*)d_in[7];
    const float* ln2_b  = (const float*)d_in[8];
    const float* w1     = (const float*)d_in[9];
    const float* b1     = (const float*)d_in[10];
    const float* w2     = (const float*)d_in[11];
    const float* b2     = (const float*)d_in[12];

    float* h = (float*)d_out;   // [MROWS, DIM] f32 running residual

    // workspace: hn_bf 4MB | z_bf 4MB | qkv_f32 25.2MB (f1_bf aliased) | wT_bf 12.6MB
    u16*   hn  = (u16*)d_ws;
    u16*   zb  = hn + (size_t)MROWS * DIM;
    float* qkv = (float*)(zb + (size_t)MROWS * DIM);
    u16*   f1  = (u16*)qkv;     // alias: qkv dead before f1 written
    u16*   wT  = (u16*)(qkv + (size_t)MROWS * 3 * INNER);

    const size_t WT_LAYER = (size_t)DIM * 3 * INNER + (size_t)INNER * DIM
                          + (size_t)DIM * MLP_D + (size_t)MLP_D * DIM;  // 3,145,728

    // h = x
    hipMemcpyAsync(h, x, (size_t)MROWS * DIM * sizeof(float),
                   hipMemcpyDeviceToDevice, stream);

    // Transpose-convert all weights to bf16 [N,K]
    for (int d = 0; d < DEPTH; ++d) {
        u16* wqkvT = wT + d * WT_LAYER;
        u16* woutT = wqkvT + (size_t)3 * INNER * DIM;
        u16* w1T   = woutT + (size_t)DIM * INNER;
        u16* w2T   = w1T   + (size_t)MLP_D * DIM;
        transpose_bf16_kernel<<<dim3(3 * INNER / 64, DIM / 64), 256, 0, stream>>>(
            w_qkv + (size_t)d * DIM * 3 * INNER, wqkvT, DIM, 3 * INNER);
        transpose_bf16_kernel<<<dim3(INNER / 64, DIM / 64), 256, 0, stream>>>(
            w_out + (size_t)d * INNER * DIM, woutT, INNER, DIM);
        transpose_bf16_kernel<<<dim3(MLP_D / 64, DIM / 64), 256, 0, stream>>>(
            w1 + (size_t)d * DIM * MLP_D, w1T, DIM, MLP_D);
        transpose_bf16_kernel<<<dim3(DIM / 64, MLP_D / 64), 256, 0, stream>>>(
            w2 + (size_t)d * MLP_D * DIM, w2T, MLP_D, DIM);
    }

    for (int d = 0; d < DEPTH; ++d) {
        u16* wqkvT = wT + d * WT_LAYER;
        u16* woutT = wqkvT + (size_t)3 * INNER * DIM;
        u16* w1T   = woutT + (size_t)DIM * INNER;
        u16* w2T   = w1T   + (size_t)MLP_D * DIM;

        // hn = bf16(LN1(h))
        ln_kernel<<<MROWS / 4, 256, 0, stream>>>(h, ln1_g + d * DIM, ln1_b + d * DIM, hn);

        // qkv(f32) = hn @ w_qkv   [4096,512]@[512,1536]
        gemm_bf16<128, 128, 4, 4, 0><<<dim3(3 * INNER / 128, MROWS / 128), 256, 0, stream>>>(
            hn, wqkvT, nullptr, nullptr, qkv, MROWS, 3 * INNER, DIM);

        // zb(bf16) = attention(qkv, mask)
        attn_kernel<<<dim3(BSZ * HEADS, SEQ / 64), 256, 0, stream>>>(qkv, mask, zb);

        // h += zb @ w_out + b_out   [4096,512]@[512,512]
        gemm_bf16<128, 64, 4, 2, 2><<<dim3(DIM / 64, MROWS / 128), 256, 0, stream>>>(
            zb, woutT, b_out + d * DIM, h, h, MROWS, DIM, INNER);

        // hn = bf16(LN2(h))
        ln_kernel<<<MROWS / 4, 256, 0, stream>>>(h, ln2_g + d * DIM, ln2_b + d * DIM, hn);

        // f1(bf16) = gelu(hn @ w1 + b1)   [4096,512]@[512,2048]
        gemm_bf16<128, 128, 4, 4, 1><<<dim3(MLP_D / 128, MROWS / 128), 256, 0, stream>>>(
            hn, w1T, b1 + d * MLP_D, nullptr, f1, MROWS, MLP_D, DIM);

        // h += f1 @ w2 + b2   [4096,2048]@[2048,512]
        gemm_bf16<128, 64, 4, 2, 2><<<dim3(DIM / 64, MROWS / 128), 256, 0, stream>>>(
            f1, w2T, b2 + d * DIM, h, h, MROWS, DIM, MLP_D);
    }
}

// Round 4
// 430.107 us; speedup vs baseline: 5.0277x; 5.0277x over previous
//
#include <hip/hip_runtime.h>
#include <math.h>

// Problem constants
#define DEPTH 2
#define DIM   512
#define HEADS 8
#define DH    64
#define INNER 512
#define MLP_D 2048
#define BSZ   2
#define SEQ   2048
#define MROWS (BSZ*SEQ)          // 4096
#define SCALE 0.125f             // DH^-0.5
#define LN_EPS 1e-5f

typedef unsigned short u16;
typedef unsigned int   u32;
typedef __attribute__((ext_vector_type(8))) unsigned short u16x8;
typedef __attribute__((ext_vector_type(4))) unsigned short u16x4;
typedef __attribute__((ext_vector_type(8))) short          s16x8;
typedef __attribute__((ext_vector_type(4))) float          f32x4;

// fp32 -> bf16 round-to-nearest-even
__device__ __forceinline__ u16 f2bf(float f) {
    u32 u = __float_as_uint(f);
    u += 0x7fffu + ((u >> 16) & 1u);
    return (u16)(u >> 16);
}

__device__ __forceinline__ float wred_sum(float v) {
    #pragma unroll
    for (int o = 32; o; o >>= 1) v += __shfl_xor(v, o);
    return v;
}

// ---------------------------------------------------------------------------
// LayerNorm: one wave per row of 512; outputs bf16. 4 waves/block.
// ---------------------------------------------------------------------------
__global__ __launch_bounds__(256) void ln_kernel(
    const float* __restrict__ x,   // [MROWS, DIM] f32
    const float* __restrict__ g,
    const float* __restrict__ b,
    u16* __restrict__ y)           // [MROWS, DIM] bf16
{
    const int wave = threadIdx.x >> 6;
    const int lane = threadIdx.x & 63;
    const int row  = blockIdx.x * 4 + wave;
    const float* xr = x + (size_t)row * DIM;

    float4 v0 = *reinterpret_cast<const float4*>(&xr[lane * 8]);
    float4 v1 = *reinterpret_cast<const float4*>(&xr[lane * 8 + 4]);

    float s = v0.x + v0.y + v0.z + v0.w + v1.x + v1.y + v1.z + v1.w;
    s = wred_sum(s);
    const float mean = s * (1.0f / DIM);

    float d[8] = {v0.x - mean, v0.y - mean, v0.z - mean, v0.w - mean,
                  v1.x - mean, v1.y - mean, v1.z - mean, v1.w - mean};
    float ss = 0.f;
    #pragma unroll
    for (int i = 0; i < 8; ++i) ss += d[i] * d[i];
    ss = wred_sum(ss);
    const float inv = rsqrtf(ss * (1.0f / DIM) + LN_EPS);

    float4 g0 = *reinterpret_cast<const float4*>(&g[lane * 8]);
    float4 g1 = *reinterpret_cast<const float4*>(&g[lane * 8 + 4]);
    float4 b0 = *reinterpret_cast<const float4*>(&b[lane * 8]);
    float4 b1 = *reinterpret_cast<const float4*>(&b[lane * 8 + 4]);
    const float gg[8] = {g0.x, g0.y, g0.z, g0.w, g1.x, g1.y, g1.z, g1.w};
    const float bb[8] = {b0.x, b0.y, b0.z, b0.w, b1.x, b1.y, b1.z, b1.w};

    u16x8 o;
    #pragma unroll
    for (int i = 0; i < 8; ++i) o[i] = f2bf(d[i] * inv * gg[i] + bb[i]);
    *reinterpret_cast<u16x8*>(&y[(size_t)row * DIM + lane * 8]) = o;
}

// ---------------------------------------------------------------------------
// Transpose-convert: in f32 [K,N] -> out bf16 [N,K]. 64x64 tiles, 256 thr.
// ---------------------------------------------------------------------------
__global__ __launch_bounds__(256) void transpose_bf16_kernel(
    const float* __restrict__ in, u16* __restrict__ out, int K, int N)
{
    __shared__ u16 t[64][65];
    const int k0 = blockIdx.y * 64, n0 = blockIdx.x * 64;
    const int tid = threadIdx.x;
    #pragma unroll
    for (int i = 0; i < 4; ++i) {
        int idx = tid + i * 256;
        int r = idx >> 4, c4 = idx & 15;
        float4 v = *reinterpret_cast<const float4*>(&in[(size_t)(k0 + r) * N + n0 + c4 * 4]);
        t[c4 * 4 + 0][r] = f2bf(v.x);
        t[c4 * 4 + 1][r] = f2bf(v.y);
        t[c4 * 4 + 2][r] = f2bf(v.z);
        t[c4 * 4 + 3][r] = f2bf(v.w);
    }
    __syncthreads();
    #pragma unroll
    for (int i = 0; i < 2; ++i) {
        int idx = tid + i * 256;
        int r = idx >> 3, c8 = idx & 7;
        u16x8 w;
        #pragma unroll
        for (int j = 0; j < 8; ++j) w[j] = t[r][c8 * 8 + j];
        *reinterpret_cast<u16x8*>(&out[(size_t)(n0 + r) * K + k0 + c8 * 8]) = w;
    }
}

// ---------------------------------------------------------------------------
// Mask bit-pack (transposed): mask[B,L,L] int -> mbT[B][64 words][SEQ] u32.
// Wave per (b,l) row; ballot over 64 keys per iteration.
// ---------------------------------------------------------------------------
__global__ __launch_bounds__(256) void mask_pack_kernel(
    const int* __restrict__ mask, u32* __restrict__ mbT)
{
    const int wv = threadIdx.x >> 6, lane = threadIdx.x & 63;
    const int row = blockIdx.x * 4 + wv;      // b*SEQ + l
    const int b = row >> 11, l = row & (SEQ - 1);
    const int* mr = mask + (size_t)row * SEQ;
    u32* out = mbT + (size_t)b * 64 * SEQ;
    for (int it = 0; it < 32; ++it) {
        unsigned long long bal = __ballot(mr[it * 64 + lane] != 0);
        if (lane == 0) {
            out[(size_t)(2 * it) * SEQ + l]     = (u32)bal;
            out[(size_t)(2 * it + 1) * SEQ + l] = (u32)(bal >> 32);
        }
    }
}

// ---------------------------------------------------------------------------
// bf16 MFMA GEMM: C = epi(A @ B [+bias] [+Cin])
//   A: [M,K] bf16 row-major. BT: [N,K] bf16 row-major (B transposed).
//   EPI 1: Cout bf16 = gelu(acc + bias)
//   EPI 2: Cout f32 = Cin + acc + bias   (Cin==Cout ok)
//   EPI 3: attention prep: col c -> {Q: qo[h][r][d] bf16*SCALE,
//          K: ko[h][r][d] bf16, V: vo[h][d][r] bf16}   (N must be 1536)
// 256 threads = 4 waves (2x2). Wave tile (MT*16)x(NT*16). BK=32.
// ---------------------------------------------------------------------------
template<int BM, int BN, int MT, int NT, int EPI>
__global__ __launch_bounds__(256) void gemm_bf16(
    const u16* __restrict__ A, const u16* __restrict__ BT,
    const float* __restrict__ bias, const float* __restrict__ Cin,
    void* __restrict__ CoutV, u16* __restrict__ qo, u16* __restrict__ ko,
    u16* __restrict__ vo, int M, int N, int K)
{
    constexpr int BK = 32;
    constexpr int LDW = 40;                 // padded row stride (u16)
    constexpr int WC = BN / (NT * 16);      // waves along N
    constexpr int AR = (BM * BK) / (256 * 8);
    constexpr int BR = (BN * BK) / (256 * 8);

    __shared__ __align__(16) u16 As[BM * LDW];
    __shared__ __align__(16) u16 Bs[BN * LDW];

    const int tid  = threadIdx.x;
    const int lane = tid & 63;
    const int wid  = tid >> 6;
    const int wr   = wid / WC, wc = wid % WC;
    const int lr   = lane & 15, lk = lane >> 4;
    const int bm   = blockIdx.y * BM, bn = blockIdx.x * BN;

    f32x4 acc[MT][NT];
    #pragma unroll
    for (int i = 0; i < MT; ++i)
        #pragma unroll
        for (int j = 0; j < NT; ++j) {
            acc[i][j][0] = 0.f; acc[i][j][1] = 0.f;
            acc[i][j][2] = 0.f; acc[i][j][3] = 0.f;
        }

    u16x8 ar[AR], br[BR];
    #pragma unroll
    for (int i = 0; i < AR; ++i) {
        int idx = tid + i * 256, row = idx >> 2, k16 = idx & 3;
        ar[i] = *reinterpret_cast<const u16x8*>(&A[(size_t)(bm + row) * K + k16 * 8]);
    }
    #pragma unroll
    for (int i = 0; i < BR; ++i) {
        int idx = tid + i * 256, row = idx >> 2, k16 = idx & 3;
        br[i] = *reinterpret_cast<const u16x8*>(&BT[(size_t)(bn + row) * K + k16 * 8]);
    }

    const int NTILES = K / BK;
    for (int t = 0; t < NTILES; ++t) {
        __syncthreads();
        #pragma unroll
        for (int i = 0; i < AR; ++i) {
            int idx = tid + i * 256, row = idx >> 2, k16 = idx & 3;
            *reinterpret_cast<u16x8*>(&As[row * LDW + k16 * 8]) = ar[i];
        }
        #pragma unroll
        for (int i = 0; i < BR; ++i) {
            int idx = tid + i * 256, row = idx >> 2, k16 = idx & 3;
            *reinterpret_cast<u16x8*>(&Bs[row * LDW + k16 * 8]) = br[i];
        }
        __syncthreads();

        if (t + 1 < NTILES) {
            const int k0 = (t + 1) * BK;
            #pragma unroll
            for (int i = 0; i < AR; ++i) {
                int idx = tid + i * 256, row = idx >> 2, k16 = idx & 3;
                ar[i] = *reinterpret_cast<const u16x8*>(&A[(size_t)(bm + row) * K + k0 + k16 * 8]);
            }
            #pragma unroll
            for (int i = 0; i < BR; ++i) {
                int idx = tid + i * 256, row = idx >> 2, k16 = idx & 3;
                br[i] = *reinterpret_cast<const u16x8*>(&BT[(size_t)(bn + row) * K + k0 + k16 * 8]);
            }
        }

        s16x8 af[MT], bf[NT];
        #pragma unroll
        for (int mt = 0; mt < MT; ++mt)
            af[mt] = *reinterpret_cast<const s16x8*>(&As[(wr * MT * 16 + mt * 16 + lr) * LDW + lk * 8]);
        #pragma unroll
        for (int nt = 0; nt < NT; ++nt)
            bf[nt] = *reinterpret_cast<const s16x8*>(&Bs[(wc * NT * 16 + nt * 16 + lr) * LDW + lk * 8]);
        #pragma unroll
        for (int mt = 0; mt < MT; ++mt)
            #pragma unroll
            for (int nt = 0; nt < NT; ++nt)
                acc[mt][nt] = __builtin_amdgcn_mfma_f32_16x16x32_bf16(
                    af[mt], bf[nt], acc[mt][nt], 0, 0, 0);
    }

    // epilogue: lane holds D[row = lk*4+i][col = lr] per 16x16 tile
    if (EPI == 3) {
        #pragma unroll
        for (int mt = 0; mt < MT; ++mt) {
            const int rbase = bm + wr * MT * 16 + mt * 16 + lk * 4;
            #pragma unroll
            for (int nt = 0; nt < NT; ++nt) {
                const int c = bn + wc * NT * 16 + nt * 16 + lr;
                const int sec = c >> 9, hh = (c >> 6) & 7, dd = c & 63;
                if (sec == 0) {
                    #pragma unroll
                    for (int i = 0; i < 4; ++i)
                        qo[((size_t)hh * MROWS + rbase + i) * 64 + dd] =
                            f2bf(acc[mt][nt][i] * SCALE);
                } else if (sec == 1) {
                    #pragma unroll
                    for (int i = 0; i < 4; ++i)
                        ko[((size_t)hh * MROWS + rbase + i) * 64 + dd] =
                            f2bf(acc[mt][nt][i]);
                } else {
                    u16x4 o;
                    #pragma unroll
                    for (int i = 0; i < 4; ++i) o[i] = f2bf(acc[mt][nt][i]);
                    *reinterpret_cast<u16x4*>(
                        &vo[((size_t)hh * 64 + dd) * MROWS + rbase]) = o;
                }
            }
        }
        return;
    }
    #pragma unroll
    for (int mt = 0; mt < MT; ++mt) {
        #pragma unroll
        for (int i = 0; i < 4; ++i) {
            const size_t r = bm + wr * MT * 16 + mt * 16 + lk * 4 + i;
            #pragma unroll
            for (int nt = 0; nt < NT; ++nt) {
                const size_t c = bn + wc * NT * 16 + nt * 16 + lr;
                float v = acc[mt][nt][i];
                if (EPI == 1) {
                    v += bias[c];
                    v = 0.5f * v * (1.0f + erff(v * 0.70710678118654752f));
                    ((u16*)CoutV)[r * N + c] = f2bf(v);
                } else {
                    v += bias[c] + Cin[r * N + c];
                    ((float*)CoutV)[r * N + c] = v;
                }
            }
        }
    }
}

// ---------------------------------------------------------------------------
// MFMA flash attention with multiplicative mask + renorm.
//   z = sum_j e_j*m_j*v_j / (sum_j e_j*m_j + 1e-10 * sum_j e_j), e=exp(s-max)
// Swapped-operand structure: S^T = mfma(K, Q) so lane owns P for one q
// (col=lane&15) across 32 keys in regs -> lane-local softmax + shfl(16,32).
// PV as Z^T = mfma(Vt, P^T): P feeds B-operand directly from regs; the
// k-slot permutation slot(lk,i)->key=(i>=4)*16+lk*4+(i&3) is mirrored on the
// Vt A-frags via paired b64 LDS reads (k-permutation invariance => exact).
// Block: 256 thr = 4 waves; wave w owns q-rows [q0+16w, q0+16w+16).
// KV tiles of 128 keys. LDS: K[128][72] + Vt[64][136] bf16 = 35 KB.
// grid = (L/64 = 32, B*H = 16)  (x = q-block so same-head blocks co-schedule)
// ---------------------------------------------------------------------------
__global__ __launch_bounds__(256) void attn_mfma_kernel(
    const u16* __restrict__ Qb,   // [H][MROWS][64] bf16, pre-scaled
    const u16* __restrict__ Kb,   // [H][MROWS][64] bf16
    const u16* __restrict__ Vtb,  // [H][64][MROWS] bf16
    const u32* __restrict__ mbT,  // [B][64][SEQ] bit-packed mask, transposed
    u16* __restrict__ z)          // [MROWS][INNER] bf16
{
    const int bh = blockIdx.y;
    const int b = bh >> 3, h = bh & 7;
    const int q0 = blockIdx.x * 64;
    const int tid = threadIdx.x;
    const int w = tid >> 6, lane = tid & 63;
    const int lr = lane & 15, lk = lane >> 4;

    __shared__ __align__(16) u16 Ks[128 * 72];
    __shared__ __align__(16) u16 Vts[64 * 136];

    const int qrow = q0 + w * 16 + lr;            // per-batch q index
    const size_t qg = (size_t)b * SEQ + qrow;     // row in [MROWS]

    // Q B-frags: col=q=lr, k-slots d = lk*8+i (+32 for second MFMA)
    s16x8 qf0, qf1;
    {
        const u16* Qrow = Qb + ((size_t)h * MROWS + qg) * 64;
        qf0 = *reinterpret_cast<const s16x8*>(Qrow + lk * 8);
        qf1 = *reinterpret_cast<const s16x8*>(Qrow + 32 + lk * 8);
    }

    float Mx = -1e30f, Sa = 0.f, Sm = 0.f;
    f32x4 zacc[4];
    #pragma unroll
    for (int dt = 0; dt < 4; ++dt) {
        zacc[dt][0] = 0.f; zacc[dt][1] = 0.f; zacc[dt][2] = 0.f; zacc[dt][3] = 0.f;
    }

    const u16* Kbase = Kb + ((size_t)h * MROWS + (size_t)b * SEQ) * 64;
    const u16* Vbase = Vtb + (size_t)h * 64 * MROWS + (size_t)b * SEQ;
    const u32* mbase = mbT + (size_t)b * 64 * SEQ;

    for (int kv0 = 0; kv0 < SEQ; kv0 += 128) {
        // ---- issue global loads (K, Vt tiles + mask words) ----
        u16x8 kr[4], vr[4];
        #pragma unroll
        for (int i = 0; i < 4; ++i) {
            int idx = tid + i * 256;
            int row = idx >> 3, c8 = idx & 7;
            kr[i] = *reinterpret_cast<const u16x8*>(
                Kbase + (size_t)(kv0 + row) * 64 + c8 * 8);
        }
        #pragma unroll
        for (int i = 0; i < 4; ++i) {
            int idx = tid + i * 256;
            int row = idx >> 4, c = idx & 15;
            vr[i] = *reinterpret_cast<const u16x8*>(
                Vbase + (size_t)row * MROWS + kv0 + c * 8);
        }
        u32 mw[4];
        #pragma unroll
        for (int j = 0; j < 4; ++j)
            mw[j] = mbase[(size_t)(kv0 / 32 + j) * SEQ + qrow];

        __syncthreads();   // previous tile fully consumed
        #pragma unroll
        for (int i = 0; i < 4; ++i) {
            int idx = tid + i * 256;
            int row = idx >> 3, c8 = idx & 7;
            *reinterpret_cast<u16x8*>(&Ks[row * 72 + c8 * 8]) = kr[i];
        }
        #pragma unroll
        for (int i = 0; i < 4; ++i) {
            int idx = tid + i * 256;
            int row = idx >> 4, c = idx & 15;
            *reinterpret_cast<u16x8*>(&Vts[row * 136 + c * 8]) = vr[i];
        }
        __syncthreads();   // tile ready

        // ---- S^T tile: st[mt] holds S[key=mt*16+lk*4+i][q=lr] ----
        f32x4 st[8];
        #pragma unroll
        for (int mt = 0; mt < 8; ++mt) {
            st[mt][0] = 0.f; st[mt][1] = 0.f; st[mt][2] = 0.f; st[mt][3] = 0.f;
        }
        #pragma unroll
        for (int mt = 0; mt < 8; ++mt) {
            const s16x8 a0 = *reinterpret_cast<const s16x8*>(
                &Ks[(mt * 16 + lr) * 72 + lk * 8]);
            const s16x8 a1 = *reinterpret_cast<const s16x8*>(
                &Ks[(mt * 16 + lr) * 72 + 32 + lk * 8]);
            st[mt] = __builtin_amdgcn_mfma_f32_16x16x32_bf16(a0, qf0, st[mt], 0, 0, 0);
            st[mt] = __builtin_amdgcn_mfma_f32_16x16x32_bf16(a1, qf1, st[mt], 0, 0, 0);
        }

        // ---- online softmax (per q = lr; keys split across lk groups) ----
        float ml = -1e30f;
        #pragma unroll
        for (int mt = 0; mt < 8; ++mt)
            #pragma unroll
            for (int i = 0; i < 4; ++i) ml = fmaxf(ml, st[mt][i]);
        ml = fmaxf(ml, __shfl_xor(ml, 16));
        ml = fmaxf(ml, __shfl_xor(ml, 32));
        const float Mn = fmaxf(Mx, ml);
        const float rsc = __expf(Mx - Mn);
        Mx = Mn;

        float ta = 0.f, tm = 0.f;
        #pragma unroll
        for (int mt = 0; mt < 8; ++mt) {
            const u32 wsh = mw[mt >> 1] >> ((mt & 1) * 16 + lk * 4);
            #pragma unroll
            for (int i = 0; i < 4; ++i) {
                float e = __expf(st[mt][i] - Mn);
                ta += e;
                float em = ((wsh >> i) & 1u) ? e : 0.f;
                tm += em;
                st[mt][i] = em;
            }
        }
        ta += __shfl_xor(ta, 16); ta += __shfl_xor(ta, 32);
        tm += __shfl_xor(tm, 16); tm += __shfl_xor(tm, 32);
        Sa = Sa * rsc + ta;
        Sm = Sm * rsc + tm;
        #pragma unroll
        for (int dt = 0; dt < 4; ++dt)
            #pragma unroll
            for (int i = 0; i < 4; ++i) zacc[dt][i] *= rsc;

        // ---- PV: Z^T[dh][q] += Vt-frag x P-frag, 4 k-steps of 32 keys ----
        #pragma unroll
        for (int s = 0; s < 4; ++s) {
            s16x8 pf;
            #pragma unroll
            for (int i = 0; i < 4; ++i) {
                pf[i]     = (short)f2bf(st[2 * s][i]);
                pf[i + 4] = (short)f2bf(st[2 * s + 1][i]);
            }
            #pragma unroll
            for (int dt = 0; dt < 4; ++dt) {
                const u16* vrow = &Vts[(dt * 16 + lr) * 136 + s * 32 + lk * 4];
                u16x4 v0 = *reinterpret_cast<const u16x4*>(vrow);
                u16x4 v1 = *reinterpret_cast<const u16x4*>(vrow + 16);
                s16x8 av;
                #pragma unroll
                for (int i = 0; i < 4; ++i) {
                    av[i]     = (short)v0[i];
                    av[i + 4] = (short)v1[i];
                }
                zacc[dt] = __builtin_amdgcn_mfma_f32_16x16x32_bf16(av, pf, zacc[dt], 0, 0, 0);
            }
        }
    }

    // ---- finalize: lane holds Z[q=lr][dh=dt*16+lk*4+i] ----
    const float inv = 1.0f / (Sm + 1e-10f * Sa);
    #pragma unroll
    for (int dt = 0; dt < 4; ++dt) {
        u16x4 o;
        #pragma unroll
        for (int i = 0; i < 4; ++i) o[i] = f2bf(zacc[dt][i] * inv);
        *reinterpret_cast<u16x4*>(
            &z[qg * INNER + h * 64 + dt * 16 + lk * 4]) = o;
    }
}

// ---------------------------------------------------------------------------
// Launch
// ---------------------------------------------------------------------------
extern "C" void kernel_launch(void* const* d_in, const int* in_sizes, int n_in,
                              void* d_out, int out_size, void* d_ws, size_t ws_size,
                              hipStream_t stream) {
    const float* x      = (const float*)d_in[0];
    const int*   mask   = (const int*)  d_in[1];
    const float* ln1_g  = (const float*)d_in[2];
    const float* ln1_b  = (const float*)d_in[3];
    const float* w_qkv  = (const float*)d_in[4];
    const float* w_out  = (const float*)d_in[5];
    const float* b_out  = (const float*)d_in[6];
    const float* ln2_g  = (const float*)d_in[7];
    const float* ln2_b  = (const float*)d_in[8];
    const float* w1     = (const float*)d_in[9];
    const float* b1     = (const float*)d_in[10];
    const float* w2     = (const float*)d_in[11];
    const float* b2     = (const float*)d_in[12];

    float* h = (float*)d_out;   // [MROWS, DIM] f32 running residual

    // workspace layout (u16 units unless noted):
    //   hn 4MB | zb 4MB | mbT 1MB | wT 12.6MB | big 16MB (Qb|Kb|Vtb, f1 alias)
    u16* hn  = (u16*)d_ws;
    u16* zb  = hn + (size_t)MROWS * DIM;
    u32* mbT = (u32*)(zb + (size_t)MROWS * DIM);
    u16* wT  = (u16*)(mbT + (size_t)BSZ * 64 * SEQ);
    const size_t WT_LAYER = (size_t)DIM * 3 * INNER + (size_t)INNER * DIM
                          + (size_t)DIM * MLP_D + (size_t)MLP_D * DIM;
    u16* big = wT + DEPTH * WT_LAYER;
    u16* Qb  = big;
    u16* Kb  = Qb + (size_t)HEADS * MROWS * 64;
    u16* Vtb = Kb + (size_t)HEADS * MROWS * 64;
    u16* f1  = big;   // [MROWS][MLP_D] aliases Qb/Kb/Vtb (dead by then)

    // h = x
    hipMemcpyAsync(h, x, (size_t)MROWS * DIM * sizeof(float),
                   hipMemcpyDeviceToDevice, stream);

    // one-time prep: mask bit-pack + weight transposes
    mask_pack_kernel<<<MROWS / 4, 256, 0, stream>>>(mask, mbT);
    for (int d = 0; d < DEPTH; ++d) {
        u16* wqkvT = wT + d * WT_LAYER;
        u16* woutT = wqkvT + (size_t)3 * INNER * DIM;
        u16* w1T   = woutT + (size_t)DIM * INNER;
        u16* w2T   = w1T   + (size_t)MLP_D * DIM;
        transpose_bf16_kernel<<<dim3(3 * INNER / 64, DIM / 64), 256, 0, stream>>>(
            w_qkv + (size_t)d * DIM * 3 * INNER, wqkvT, DIM, 3 * INNER);
        transpose_bf16_kernel<<<dim3(INNER / 64, DIM / 64), 256, 0, stream>>>(
            w_out + (size_t)d * INNER * DIM, woutT, INNER, DIM);
        transpose_bf16_kernel<<<dim3(MLP_D / 64, DIM / 64), 256, 0, stream>>>(
            w1 + (size_t)d * DIM * MLP_D, w1T, DIM, MLP_D);
        transpose_bf16_kernel<<<dim3(DIM / 64, MLP_D / 64), 256, 0, stream>>>(
            w2 + (size_t)d * MLP_D * DIM, w2T, MLP_D, DIM);
    }

    for (int d = 0; d < DEPTH; ++d) {
        u16* wqkvT = wT + d * WT_LAYER;
        u16* woutT = wqkvT + (size_t)3 * INNER * DIM;
        u16* w1T   = woutT + (size_t)DIM * INNER;
        u16* w2T   = w1T   + (size_t)MLP_D * DIM;

        // hn = bf16(LN1(h))
        ln_kernel<<<MROWS / 4, 256, 0, stream>>>(h, ln1_g + d * DIM, ln1_b + d * DIM, hn);

        // QKV GEMM with attention-prep epilogue -> Qb/Kb/Vtb (bf16)
        gemm_bf16<128, 128, 4, 4, 3><<<dim3(3 * INNER / 128, MROWS / 128), 256, 0, stream>>>(
            hn, wqkvT, nullptr, nullptr, nullptr, Qb, Kb, Vtb, MROWS, 3 * INNER, DIM);

        // zb = attention(Qb, Kb, Vtb, mask)
        attn_mfma_kernel<<<dim3(SEQ / 64, BSZ * HEADS), 256, 0, stream>>>(
            Qb, Kb, Vtb, mbT, zb);

        // h += zb @ w_out + b_out
        gemm_bf16<128, 64, 4, 2, 2><<<dim3(DIM / 64, MROWS / 128), 256, 0, stream>>>(
            zb, woutT, b_out + d * DIM, h, h, nullptr, nullptr, nullptr, MROWS, DIM, INNER);

        // hn = bf16(LN2(h))
        ln_kernel<<<MROWS / 4, 256, 0, stream>>>(h, ln2_g + d * DIM, ln2_b + d * DIM, hn);

        // f1 = gelu(hn @ w1 + b1)
        gemm_bf16<128, 128, 4, 4, 1><<<dim3(MLP_D / 128, MROWS / 128), 256, 0, stream>>>(
            hn, w1T, b1 + d * MLP_D, nullptr, f1, nullptr, nullptr, nullptr, MROWS, MLP_D, DIM);

        // h += f1 @ w2 + b2
        gemm_bf16<128, 64, 4, 2, 2><<<dim3(DIM / 64, MROWS / 128), 256, 0, stream>>>(
            f1, w2T, b2 + d * DIM, h, h, nullptr, nullptr, nullptr, MROWS, DIM, MLP_D);
    }
}